// Round 1
// baseline (133.960 us; speedup 1.0000x reference)
//
#include <hip/hip_runtime.h>
#include <math.h>

#define T_TOTAL 2048
#define B_TOTAL 4096
#define NCHUNK  32
#define TCHUNK  (T_TOTAL / NCHUNK)   // 64

__device__ __forceinline__ int delta_of(float p, float q) {
    // is_push = p>=0.5 && p>=q ; is_pop = q>=0.5 && q>p
    return (p >= 0.5f && p >= q) ? 1 : ((q >= 0.5f && q > p) ? -1 : 0);
}

// Pass 1: per-(chunk, b) sum of deltas -> partial[c*B + b]
__global__ void scan_pass1(const float* __restrict__ x, int* __restrict__ partial) {
    const int b = blockIdx.x * blockDim.x + threadIdx.x;  // 0..B-1
    const int c = blockIdx.y;                             // 0..NCHUNK-1
    const float2* __restrict__ x2 = (const float2*)x;
    const int t0 = c * TCHUNK;
    int sum = 0;
#pragma unroll 4
    for (int t = t0; t < t0 + TCHUNK; ++t) {
        float2 v = x2[(size_t)t * B_TOTAL + b];
        sum += delta_of(v.x, v.y);
    }
    partial[c * B_TOTAL + b] = sum;
}

// Pass 2: in-place exclusive scan of the NCHUNK partials per b
__global__ void scan_pass2(int* __restrict__ partial) {
    const int b = blockIdx.x * blockDim.x + threadIdx.x;
    int off = 0;
#pragma unroll
    for (int c = 0; c < NCHUNK; ++c) {
        int v = partial[c * B_TOTAL + b];
        partial[c * B_TOTAL + b] = off;
        off += v;
    }
}

// Pass 3: recompute deltas, accumulate from exclusive prefix, emit {count, tanh}
__global__ void scan_pass3(const float* __restrict__ x, const int* __restrict__ partial,
                           float* __restrict__ out) {
    const int b = blockIdx.x * blockDim.x + threadIdx.x;
    const int c = blockIdx.y;
    const float2* __restrict__ x2 = (const float2*)x;
    float2* __restrict__ o2 = (float2*)out;
    const int t0 = c * TCHUNK;
    int count = partial[c * B_TOTAL + b];
#pragma unroll 4
    for (int t = t0; t < t0 + TCHUNK; ++t) {
        float2 v = x2[(size_t)t * B_TOTAL + b];
        count += delta_of(v.x, v.y);
        float fc = (float)count;
        float2 w;
        w.x = fc;
        w.y = tanhf(fc);
        o2[(size_t)t * B_TOTAL + b] = w;
    }
}

// Fallback: one thread per batch column, fully sequential over T.
__global__ void naive_scan(const float* __restrict__ x, float* __restrict__ out) {
    const int b = blockIdx.x * blockDim.x + threadIdx.x;
    if (b >= B_TOTAL) return;
    const float2* __restrict__ x2 = (const float2*)x;
    float2* __restrict__ o2 = (float2*)out;
    int count = 0;
    for (int t = 0; t < T_TOTAL; ++t) {
        float2 v = x2[(size_t)t * B_TOTAL + b];
        count += delta_of(v.x, v.y);
        float fc = (float)count;
        float2 w;
        w.x = fc;
        w.y = tanhf(fc);
        o2[(size_t)t * B_TOTAL + b] = w;
    }
}

extern "C" void kernel_launch(void* const* d_in, const int* in_sizes, int n_in,
                              void* d_out, int out_size, void* d_ws, size_t ws_size,
                              hipStream_t stream) {
    const float* x = (const float*)d_in[0];
    // d_in[1] is state0 (all zeros) — initial count is 0, so it is unused.
    float* out = (float*)d_out;

    const size_t partial_bytes = (size_t)NCHUNK * B_TOTAL * sizeof(int);  // 512 KiB
    if (ws_size < partial_bytes) {
        // Safety fallback (should not trigger)
        naive_scan<<<dim3((B_TOTAL + 255) / 256), dim3(256), 0, stream>>>(x, out);
        return;
    }
    int* partial = (int*)d_ws;

    dim3 block(256);
    dim3 grid1(B_TOTAL / 256, NCHUNK);  // (16, 32) = 512 blocks
    scan_pass1<<<grid1, block, 0, stream>>>(x, partial);
    scan_pass2<<<dim3(B_TOTAL / 256), block, 0, stream>>>(partial);
    scan_pass3<<<grid1, block, 0, stream>>>(x, partial, out);
}

// Round 2
// 115.474 us; speedup vs baseline: 1.1601x; 1.1601x over previous
//
#include <hip/hip_runtime.h>
#include <math.h>

#define T_TOTAL 2048
#define B_TOTAL 4096
#define B2      (B_TOTAL / 2)        // float4 columns-pairs per row = 2048
#define NCHUNK  64
#define TCHUNK  (T_TOTAL / NCHUNK)   // 32

__device__ __forceinline__ int delta_of(float p, float q) {
    // is_push = p>=0.5 && p>=q ; is_pop = q>=0.5 && q>p
    return (p >= 0.5f && p >= q) ? 1 : ((q >= 0.5f && q > p) ? -1 : 0);
}

__device__ __forceinline__ float fast_tanh(float x) {
    // tanh(x) = 1 - 2/(exp2(2x*log2e)+1); exact at 0, saturates to +-1.
    float e = __builtin_amdgcn_exp2f(x * 2.885390081777927f);
    return 1.0f - 2.0f / (e + 1.0f);
}

// Pass 1: per-(chunk, pair) delta computation.
// Emits: packed 2-bit deltas (ulonglong2 per thread) + per-column chunk sums (int2).
__global__ void scan_pass1(const float* __restrict__ x,
                           int* __restrict__ partial,          // [NCHUNK][B_TOTAL]
                           ulonglong2* __restrict__ packed) {  // [NCHUNK][B2]
    const int p = blockIdx.x * blockDim.x + threadIdx.x;  // 0..B2-1 (column pair)
    const int c = blockIdx.y;                             // 0..NCHUNK-1
    const float4* __restrict__ x4 = (const float4*)x;
    const int t0 = c * TCHUNK;

    int s0 = 0, s1 = 0;
    unsigned long long w0 = 0ull, w1 = 0ull;

#pragma unroll
    for (int t = 0; t < 16; ++t) {
        float4 v = x4[(size_t)(t0 + t) * B2 + p];
        int d0 = delta_of(v.x, v.y);
        int d1 = delta_of(v.z, v.w);
        s0 += d0; s1 += d1;
        unsigned int nib = (unsigned int)(d0 & 3) | ((unsigned int)(d1 & 3) << 2);
        w0 |= (unsigned long long)nib << (4 * t);
    }
#pragma unroll
    for (int t = 16; t < 32; ++t) {
        float4 v = x4[(size_t)(t0 + t) * B2 + p];
        int d0 = delta_of(v.x, v.y);
        int d1 = delta_of(v.z, v.w);
        s0 += d0; s1 += d1;
        unsigned int nib = (unsigned int)(d0 & 3) | ((unsigned int)(d1 & 3) << 2);
        w1 |= (unsigned long long)nib << (4 * (t - 16));
    }

    ulonglong2 w; w.x = w0; w.y = w1;
    packed[(size_t)c * B2 + p] = w;
    int2 s; s.x = s0; s.y = s1;
    ((int2*)partial)[(size_t)c * B2 + p] = s;   // columns 2p, 2p+1
}

// Pass 2: in-place exclusive scan of NCHUNK chunk-sums per column.
__global__ void scan_pass2(int* __restrict__ partial) {
    const int b = blockIdx.x * blockDim.x + threadIdx.x;  // 0..B_TOTAL-1
    int off = 0;
#pragma unroll
    for (int c = 0; c < NCHUNK; ++c) {
        int v = partial[(size_t)c * B_TOTAL + b];
        partial[(size_t)c * B_TOTAL + b] = off;
        off += v;
    }
}

__device__ __forceinline__ int sext2(unsigned int bits2) {
    return ((int)(bits2 << 30)) >> 30;  // 2-bit signed: 00->0, 01->+1, 11->-1
}

// Pass 3: decode packed deltas, accumulate from exclusive prefix, emit {count,tanh}x2.
__global__ void scan_pass3(const int* __restrict__ partial,
                           const ulonglong2* __restrict__ packed,
                           float* __restrict__ out) {
    const int p = blockIdx.x * blockDim.x + threadIdx.x;
    const int c = blockIdx.y;
    float4* __restrict__ o4 = (float4*)out;
    const int t0 = c * TCHUNK;

    int2 pr = ((const int2*)partial)[(size_t)c * B2 + p];
    int c0 = pr.x, c1 = pr.y;
    ulonglong2 w = packed[(size_t)c * B2 + p];

#pragma unroll
    for (int t = 0; t < 16; ++t) {
        unsigned int nib = (unsigned int)(w.x >> (4 * t)) & 0xFu;
        c0 += sext2(nib & 3u);
        c1 += sext2(nib >> 2);
        float f0 = (float)c0, f1 = (float)c1;
        float4 o; o.x = f0; o.y = fast_tanh(f0); o.z = f1; o.w = fast_tanh(f1);
        o4[(size_t)(t0 + t) * B2 + p] = o;
    }
#pragma unroll
    for (int t = 16; t < 32; ++t) {
        unsigned int nib = (unsigned int)(w.y >> (4 * (t - 16))) & 0xFu;
        c0 += sext2(nib & 3u);
        c1 += sext2(nib >> 2);
        float f0 = (float)c0, f1 = (float)c1;
        float4 o; o.x = f0; o.y = fast_tanh(f0); o.z = f1; o.w = fast_tanh(f1);
        o4[(size_t)(t0 + t) * B2 + p] = o;
    }
}

// Fallback: one thread per batch column, fully sequential over T.
__global__ void naive_scan(const float* __restrict__ x, float* __restrict__ out) {
    const int b = blockIdx.x * blockDim.x + threadIdx.x;
    if (b >= B_TOTAL) return;
    const float2* __restrict__ x2 = (const float2*)x;
    float2* __restrict__ o2 = (float2*)out;
    int count = 0;
    for (int t = 0; t < T_TOTAL; ++t) {
        float2 v = x2[(size_t)t * B_TOTAL + b];
        count += delta_of(v.x, v.y);
        float fc = (float)count;
        float2 w; w.x = fc; w.y = tanhf(fc);
        o2[(size_t)t * B_TOTAL + b] = w;
    }
}

extern "C" void kernel_launch(void* const* d_in, const int* in_sizes, int n_in,
                              void* d_out, int out_size, void* d_ws, size_t ws_size,
                              hipStream_t stream) {
    const float* x = (const float*)d_in[0];
    float* out = (float*)d_out;

    const size_t partial_bytes = (size_t)NCHUNK * B_TOTAL * sizeof(int);        // 1 MiB
    const size_t packed_bytes  = (size_t)NCHUNK * B2 * sizeof(ulonglong2);      // 2 MiB
    if (ws_size < partial_bytes + packed_bytes) {
        naive_scan<<<dim3((B_TOTAL + 255) / 256), dim3(256), 0, stream>>>(x, out);
        return;
    }
    int* partial = (int*)d_ws;
    ulonglong2* packed = (ulonglong2*)((char*)d_ws + partial_bytes);

    dim3 block(256);
    dim3 grid1(B2 / 256, NCHUNK);  // (8, 64) = 512 blocks
    scan_pass1<<<grid1, block, 0, stream>>>(x, partial, packed);
    scan_pass2<<<dim3(B_TOTAL / 256), block, 0, stream>>>(partial);
    scan_pass3<<<grid1, block, 0, stream>>>(partial, packed, out);
}